// Round 1
// baseline (304.482 us; speedup 1.0000x reference)
//
#include <hip/hip_runtime.h>
#include <hip/hip_bf16.h>
#include <math.h>

constexpr int H   = 256;
constexpr int KNB = 32;
constexpr int TPB = 256;
constexpr int TLOC = 8;   // per-thread local top-K candidates

__device__ __forceinline__ float gelu_tanh(float x) {
    // jax.nn.gelu default approximate=True (tanh form)
    float x3 = x * x * x;
    return 0.5f * x * (1.0f + tanhf(0.7978845608028654f * (x + 0.044715f * x3)));
}

__global__ __launch_bounds__(TPB)
void supernode_fused(const float* __restrict__ pos, int N,
                     const int* __restrict__ supidx,
                     const float* __restrict__ W1, const float* __restrict__ b1,
                     const float* __restrict__ W2, const float* __restrict__ b2,
                     const float* __restrict__ Wp, const float* __restrict__ bp,
                     float* __restrict__ out)
{
    __shared__ float mt[H * KNB];     // 32 KB: msg_in transposed [i][k]
    __shared__ float rf[KNB][4];      // rel features (rx,ry,rz,d)
    __shared__ int   sel[KNB];        // selected neighbor indices
    __shared__ float pk[8 * H];       // 8 KB partial k-sums of gelu(h)
    __shared__ float hb[H];           // mean_k h
    __shared__ float feats[2 * H];    // [sup_emb | agg]
    __shared__ float wv[4];
    __shared__ int   wi4[4];
    __shared__ int   bci;

    const int s = blockIdx.x;
    const int t = threadIdx.x;

    const int sidx = supidx[s];
    const float sx = pos[3 * sidx + 0];
    const float sy = pos[3 * sidx + 1];
    const float sz = pos[3 * sidx + 2];

    // ---------------- phase 1: exact kNN (top-32 smallest dist2) ----------------
    float ld[TLOC];
    int   li[TLOC];
#pragma unroll
    for (int j = 0; j < TLOC; j++) { ld[j] = INFINITY; li[j] = 0x7fffffff; }
    float worst = INFINITY;
    int   wslot = 0;

    for (int i = t; i < N; i += TPB) {
        float px = pos[3 * i + 0], py = pos[3 * i + 1], pz = pos[3 * i + 2];
        float dx = sx - px, dy = sy - py, dz = sz - pz;
        float d2 = dx * dx + dy * dy + dz * dz;
        if (d2 < worst) {
            // replace current worst slot (unrolled: keep arrays in registers)
#pragma unroll
            for (int j = 0; j < TLOC; j++) if (j == wslot) { ld[j] = d2; li[j] = i; }
            // recompute worst
            worst = ld[0]; wslot = 0;
#pragma unroll
            for (int j = 1; j < TLOC; j++) if (ld[j] > worst) { worst = ld[j]; wslot = j; }
        }
    }

    // 32 rounds of block-wide min extraction (tie-break: smaller point index)
    for (int r = 0; r < KNB; r++) {
        float v = INFINITY; int gi = 0x7fffffff;
#pragma unroll
        for (int j = 0; j < TLOC; j++) {
            bool b = (ld[j] < v) || (ld[j] == v && li[j] < gi);
            if (b) { v = ld[j]; gi = li[j]; }
        }
#pragma unroll
        for (int off = 32; off; off >>= 1) {
            float ov = __shfl_xor(v, off);
            int   oi = __shfl_xor(gi, off);
            if (ov < v || (ov == v && oi < gi)) { v = ov; gi = oi; }
        }
        const int wid = t >> 6;
        if ((t & 63) == 0) { wv[wid] = v; wi4[wid] = gi; }
        __syncthreads();
        if (t == 0) {
            float bv = wv[0]; int bi = wi4[0];
            for (int w = 1; w < 4; w++)
                if (wv[w] < bv || (wv[w] == bv && wi4[w] < bi)) { bv = wv[w]; bi = wi4[w]; }
            sel[r] = bi; bci = bi;
        }
        __syncthreads();
        const int bi = bci;
#pragma unroll
        for (int j = 0; j < TLOC; j++) if (li[j] == bi) { ld[j] = INFINITY; li[j] = 0x7fffffff; }
    }

    // ---------------- phase 2: rel features + sincos embed ----------------
    if (t < KNB) {
        int ni = sel[t];
        float px = pos[3 * ni + 0], py = pos[3 * ni + 1], pz = pos[3 * ni + 2];
        float rx = sx - px, ry = sy - py, rz = sz - pz;
        float dd = sqrtf(rx * rx + ry * ry + rz * rz);
        rf[t][0] = rx; rf[t][1] = ry; rf[t][2] = rz; rf[t][3] = dd;
    }
    __syncthreads();

    constexpr float L2_10000 = 13.287712379549449f;
    // 4096 (k,c,f) items; each produces sin+cos into transposed msg_in
#pragma unroll
    for (int n = 0; n < 16; n++) {
        int item = t + n * TPB;
        int f = item & 31;
        int c = (item >> 5) & 3;
        int k = item >> 7;
        float ang = rf[k][c] * exp2f(-(float)f * (L2_10000 / 32.f));
        mt[(c * 64 + f) * KNB + k]      = sinf(ang);
        mt[(c * 64 + 32 + f) * KNB + k] = cosf(ang);
    }
    __syncthreads();

    // ---------------- GEMM1: h = gelu(msg_in @ W1 + b1), then mean over k ------
    const int jg = t & 31, kg = t >> 5;
    const int j0 = jg * 8, k0 = kg * 4;

    float acc[4][8];
#pragma unroll
    for (int jj = 0; jj < 8; jj++) {
        float bv = b1[j0 + jj];
#pragma unroll
        for (int kk = 0; kk < 4; kk++) acc[kk][jj] = bv;
    }

#pragma unroll 2
    for (int i = 0; i < H; i++) {
        float4 a = *(const float4*)&mt[i * KNB + k0];
        const float* wr = W1 + i * H + j0;
        float4 w0 = *(const float4*)wr;
        float4 w1 = *(const float4*)(wr + 4);
        float av[4] = { a.x, a.y, a.z, a.w };
        float wv8[8] = { w0.x, w0.y, w0.z, w0.w, w1.x, w1.y, w1.z, w1.w };
#pragma unroll
        for (int kk = 0; kk < 4; kk++)
#pragma unroll
            for (int jj = 0; jj < 8; jj++)
                acc[kk][jj] += av[kk] * wv8[jj];
    }

#pragma unroll
    for (int jj = 0; jj < 8; jj++) {
        float s4 = gelu_tanh(acc[0][jj]) + gelu_tanh(acc[1][jj])
                 + gelu_tanh(acc[2][jj]) + gelu_tanh(acc[3][jj]);
        pk[kg * H + j0 + jj] = s4;
    }
    __syncthreads();

    {
        float hbv = 0.f;
#pragma unroll
        for (int g = 0; g < 8; g++) hbv += pk[g * H + t];
        hb[t] = hbv * (1.0f / 32.0f);
    }
    __syncthreads();

    // ---------------- GEMM2 (matvec): agg = hb @ W2 + b2 ----------------
    {
        float a0 = b2[t], a1 = 0.f, a2 = 0.f, a3 = 0.f;
        for (int i = 0; i < H; i += 4) {
            a0 += hb[i + 0] * W2[(i + 0) * H + t];
            a1 += hb[i + 1] * W2[(i + 1) * H + t];
            a2 += hb[i + 2] * W2[(i + 2) * H + t];
            a3 += hb[i + 3] * W2[(i + 3) * H + t];
        }
        feats[H + t] = (a0 + a1) + (a2 + a3);
    }

    // ---------------- supernode absolute-position embed (ndim=3) ----------------
    {
        float se = 0.f;
        if (t < 252) {
            int c = t / 84;
            int rr = t - c * 84;
            int f = (rr < 42) ? rr : rr - 42;
            float coord = (c == 0) ? sx : ((c == 1) ? sy : sz);
            float ang = coord * exp2f(-(float)f * (L2_10000 / 42.f));
            se = (rr < 42) ? sinf(ang) : cosf(ang);
        }
        feats[t] = se;
    }
    __syncthreads();

    // ---------------- final projection: out = feats @ Wp + bp ----------------
    {
        float o0 = bp[t], o1 = 0.f, o2 = 0.f, o3 = 0.f;
        for (int i = 0; i < 2 * H; i += 4) {
            o0 += feats[i + 0] * Wp[(i + 0) * H + t];
            o1 += feats[i + 1] * Wp[(i + 1) * H + t];
            o2 += feats[i + 2] * Wp[(i + 2) * H + t];
            o3 += feats[i + 3] * Wp[(i + 3) * H + t];
        }
        out[s * H + t] = (o0 + o1) + (o2 + o3);
    }
}

extern "C" void kernel_launch(void* const* d_in, const int* in_sizes, int n_in,
                              void* d_out, int out_size, void* d_ws, size_t ws_size,
                              hipStream_t stream) {
    const float* pos = (const float*)d_in[0];
    const int*   sup = (const int*)d_in[1];
    const float* W1  = (const float*)d_in[2];
    const float* b1  = (const float*)d_in[3];
    const float* W2  = (const float*)d_in[4];
    const float* b2  = (const float*)d_in[5];
    const float* Wp  = (const float*)d_in[6];
    const float* bp  = (const float*)d_in[7];

    const int N = in_sizes[0] / 3;
    const int S = in_sizes[1];
    float* out = (float*)d_out;

    supernode_fused<<<S, TPB, 0, stream>>>(pos, N, sup, W1, b1, W2, b2, Wp, bp, out);
}

// Round 2
// 284.172 us; speedup vs baseline: 1.0715x; 1.0715x over previous
//
#include <hip/hip_runtime.h>
#include <hip/hip_bf16.h>
#include <math.h>

constexpr int H    = 256;
constexpr int KNB  = 32;
constexpr int TPB  = 256;
constexpr int TLOC = 8;   // per-thread local top-K candidates

__device__ __forceinline__ float gelu_tanh(float x) {
    // jax.nn.gelu default approximate=True (tanh form)
    float x3 = x * x * x;
    return 0.5f * x * (1.0f + tanhf(0.7978845608028654f * (x + 0.044715f * x3)));
}

__global__ __launch_bounds__(TPB)
void supernode_fused(const float* __restrict__ pos, int N,
                     const int* __restrict__ supidx,
                     const float* __restrict__ W1, const float* __restrict__ b1,
                     const float* __restrict__ W2, const float* __restrict__ b2,
                     const float* __restrict__ Wp, const float* __restrict__ bp,
                     float* __restrict__ out)
{
    // 32 KB: msg_in transposed [i][k] during GEMM1; first 8 KB reused as pk after
    __shared__ float smem[H * KNB];
    __shared__ float rf[KNB][5];      // rel features (rx,ry,rz,d), stride 5 = conflict-free
    __shared__ int   sel[KNB];
    __shared__ float hb[H];
    __shared__ float feats[2 * H];
    __shared__ float wv[4];
    __shared__ int   wi4[4];
    __shared__ int   bci;

    const int s = blockIdx.x;
    const int t = threadIdx.x;

    const int sidx = supidx[s];
    const float sx = pos[3 * sidx + 0];
    const float sy = pos[3 * sidx + 1];
    const float sz = pos[3 * sidx + 2];

    // ---------------- phase 1: exact kNN (top-32 smallest dist2) ----------------
    float ld[TLOC];
    int   li[TLOC];
#pragma unroll
    for (int j = 0; j < TLOC; j++) { ld[j] = INFINITY; li[j] = 0x7fffffff; }
    float worst = INFINITY;
    int   wslot = 0;

    auto upd = [&](float d2, int i) {
        if (d2 < worst) {
#pragma unroll
            for (int j = 0; j < TLOC; j++) if (j == wslot) { ld[j] = d2; li[j] = i; }
            worst = ld[0]; wslot = 0;
#pragma unroll
            for (int j = 1; j < TLOC; j++) if (ld[j] > worst) { worst = ld[j]; wslot = j; }
        }
    };

    int base = 0;
    for (; base + 4 * TPB <= N; base += 4 * TPB) {
        const int i0 = base + t, i1 = i0 + TPB, i2 = i1 + TPB, i3 = i2 + TPB;
        float x0 = pos[3 * i0], y0 = pos[3 * i0 + 1], z0 = pos[3 * i0 + 2];
        float x1 = pos[3 * i1], y1 = pos[3 * i1 + 1], z1 = pos[3 * i1 + 2];
        float x2 = pos[3 * i2], y2 = pos[3 * i2 + 1], z2 = pos[3 * i2 + 2];
        float x3 = pos[3 * i3], y3 = pos[3 * i3 + 1], z3 = pos[3 * i3 + 2];
        float dx, dy, dz;
        dx = sx - x0; dy = sy - y0; dz = sz - z0; float d20 = dx*dx + dy*dy + dz*dz;
        dx = sx - x1; dy = sy - y1; dz = sz - z1; float d21 = dx*dx + dy*dy + dz*dz;
        dx = sx - x2; dy = sy - y2; dz = sz - z2; float d22 = dx*dx + dy*dy + dz*dz;
        dx = sx - x3; dy = sy - y3; dz = sz - z3; float d23 = dx*dx + dy*dy + dz*dz;
        upd(d20, i0); upd(d21, i1); upd(d22, i2); upd(d23, i3);
    }
    for (int i = base + t; i < N; i += TPB) {
        float px = pos[3 * i], py = pos[3 * i + 1], pz = pos[3 * i + 2];
        float dx = sx - px, dy = sy - py, dz = sz - pz;
        upd(dx*dx + dy*dy + dz*dz, i);
    }

    // 32 rounds of block-wide min extraction (tie-break: smaller point index)
    for (int r = 0; r < KNB; r++) {
        float v = INFINITY; int gi = 0x7fffffff;
#pragma unroll
        for (int j = 0; j < TLOC; j++) {
            bool b = (ld[j] < v) || (ld[j] == v && li[j] < gi);
            if (b) { v = ld[j]; gi = li[j]; }
        }
#pragma unroll
        for (int off = 32; off; off >>= 1) {
            float ov = __shfl_xor(v, off);
            int   oi = __shfl_xor(gi, off);
            if (ov < v || (ov == v && oi < gi)) { v = ov; gi = oi; }
        }
        const int wid = t >> 6;
        if ((t & 63) == 0) { wv[wid] = v; wi4[wid] = gi; }
        __syncthreads();
        if (t == 0) {
            float bv = wv[0]; int bi = wi4[0];
            for (int w = 1; w < 4; w++)
                if (wv[w] < bv || (wv[w] == bv && wi4[w] < bi)) { bv = wv[w]; bi = wi4[w]; }
            sel[r] = bi; bci = bi;
        }
        __syncthreads();
        const int bi = bci;
#pragma unroll
        for (int j = 0; j < TLOC; j++) if (li[j] == bi) { ld[j] = INFINITY; li[j] = 0x7fffffff; }
    }

    // ---------------- phase 2: rel features + sincos embed ----------------
    if (t < KNB) {
        int ni = sel[t];
        float px = pos[3 * ni], py = pos[3 * ni + 1], pz = pos[3 * ni + 2];
        float rx = sx - px, ry = sy - py, rz = sz - pz;
        float dd = sqrtf(rx * rx + ry * ry + rz * rz);
        rf[t][0] = rx; rf[t][1] = ry; rf[t][2] = rz; rf[t][3] = dd;
    }
    __syncthreads();

    constexpr float L2_10000 = 13.287712379549449f;
    // 4096 (k,c,f) items; lanes map to consecutive k -> conflict-free mt writes
#pragma unroll
    for (int n = 0; n < 16; n++) {
        int item = t + n * TPB;
        int k  = item & 31;
        int cf = item >> 5;          // 0..127
        int c  = cf >> 5;            // 0..3
        int f  = cf & 31;            // 0..31
        float ang = rf[k][c] * exp2f(-(float)f * (L2_10000 / 32.f));
        smem[(c * 64 + f) * KNB + k]      = sinf(ang);
        smem[(c * 64 + 32 + f) * KNB + k] = cosf(ang);
    }
    __syncthreads();

    // ---------------- GEMM1: h = gelu(msg_in @ W1 + b1), then mean over k ------
    const int jg = t & 31, kg = t >> 5;
    const int j0 = jg * 8, k0 = kg * 4;

    float acc[4][8];
#pragma unroll
    for (int jj = 0; jj < 8; jj++) {
        float bv = b1[j0 + jj];
#pragma unroll
        for (int kk = 0; kk < 4; kk++) acc[kk][jj] = bv;
    }

#pragma unroll 4
    for (int i = 0; i < H; i++) {
        float4 a = *(const float4*)&smem[i * KNB + k0];
        const float* wr = W1 + i * H + j0;
        float4 w0 = *(const float4*)wr;
        float4 w1 = *(const float4*)(wr + 4);
        float av[4] = { a.x, a.y, a.z, a.w };
        float wv8[8] = { w0.x, w0.y, w0.z, w0.w, w1.x, w1.y, w1.z, w1.w };
#pragma unroll
        for (int kk = 0; kk < 4; kk++)
#pragma unroll
            for (int jj = 0; jj < 8; jj++)
                acc[kk][jj] += av[kk] * wv8[jj];
    }
    __syncthreads();   // all mt reads done; smem[0..2047] becomes pk

    {
        float g4[8];
#pragma unroll
        for (int jj = 0; jj < 8; jj++)
            g4[jj] = gelu_tanh(acc[0][jj]) + gelu_tanh(acc[1][jj])
                   + gelu_tanh(acc[2][jj]) + gelu_tanh(acc[3][jj]);
        float4 v0 = { g4[0], g4[1], g4[2], g4[3] };
        float4 v1 = { g4[4], g4[5], g4[6], g4[7] };
        *(float4*)&smem[kg * H + j0]     = v0;
        *(float4*)&smem[kg * H + j0 + 4] = v1;
    }
    __syncthreads();

    {
        float hbv = 0.f;
#pragma unroll
        for (int g = 0; g < 8; g++) hbv += smem[g * H + t];
        hb[t] = hbv * (1.0f / 32.0f);
    }
    __syncthreads();

    // ---------------- GEMM2 (matvec): agg = hb @ W2 + b2 ----------------
    {
        float a[8];
#pragma unroll
        for (int u = 0; u < 8; u++) a[u] = 0.f;
        a[0] = b2[t];
        for (int i = 0; i < H; i += 8) {
#pragma unroll
            for (int u = 0; u < 8; u++)
                a[u] += hb[i + u] * W2[(i + u) * H + t];
        }
        feats[H + t] = ((a[0] + a[1]) + (a[2] + a[3])) + ((a[4] + a[5]) + (a[6] + a[7]));
    }

    // ---------------- supernode absolute-position embed (ndim=3) ----------------
    {
        float se = 0.f;
        if (t < 252) {
            int c = t / 84;
            int rr = t - c * 84;
            int f = (rr < 42) ? rr : rr - 42;
            float coord = (c == 0) ? sx : ((c == 1) ? sy : sz);
            float ang = coord * exp2f(-(float)f * (L2_10000 / 42.f));
            se = (rr < 42) ? sinf(ang) : cosf(ang);
        }
        feats[t] = se;
    }
    __syncthreads();

    // ---------------- final projection: out = feats @ Wp + bp ----------------
    {
        float o[8];
#pragma unroll
        for (int u = 0; u < 8; u++) o[u] = 0.f;
        o[0] = bp[t];
        for (int i = 0; i < 2 * H; i += 8) {
#pragma unroll
            for (int u = 0; u < 8; u++)
                o[u] += feats[i + u] * Wp[(i + u) * H + t];
        }
        out[s * H + t] = ((o[0] + o[1]) + (o[2] + o[3])) + ((o[4] + o[5]) + (o[6] + o[7]));
    }
}

extern "C" void kernel_launch(void* const* d_in, const int* in_sizes, int n_in,
                              void* d_out, int out_size, void* d_ws, size_t ws_size,
                              hipStream_t stream) {
    const float* pos = (const float*)d_in[0];
    const int*   sup = (const int*)d_in[1];
    const float* W1  = (const float*)d_in[2];
    const float* b1  = (const float*)d_in[3];
    const float* W2  = (const float*)d_in[4];
    const float* b2  = (const float*)d_in[5];
    const float* Wp  = (const float*)d_in[6];
    const float* bp  = (const float*)d_in[7];

    const int N = in_sizes[0] / 3;
    const int S = in_sizes[1];
    float* out = (float*)d_out;

    supernode_fused<<<S, TPB, 0, stream>>>(pos, N, sup, W1, b1, W2, b2, Wp, bp, out);
}